// Round 6
// baseline (96.435 us; speedup 1.0000x reference)
//
#include <hip/hip_runtime.h>
#include <hip/hip_bf16.h>

// Geometry
#define NW 64          // N*W = 4*16
#define P 128          // rows per (n,w)
#define D 96           // channels
#define PD (P*D)
#define GCH 101
#define SIM 100
#define LCH 80
#define RSQRT96 0.10206207261596577f   // 1/sqrt(96)

// ws layout (float offsets)
#define WS_SCALE 0                     // 128 floats
#define WS_Q     128                   // 64*128*96   [r][c]
#define WS_KT    (128 + 786432)        // 64*96*128   [c][r] transposed
#define WS_VO    (128 + 2*786432)      // 64*128*96   [r][c]

typedef unsigned long long ull;

// key = (ordered_u32(value) << 32) | (127 - idx): strict total order,
// ties -> lower idx wins. Matches top_k + sort-index semantics exactly.
__device__ __forceinline__ ull make_key(float a, int idx) {
  unsigned u = __float_as_uint(a);
  unsigned msk = (u & 0x80000000u) ? 0xFFFFFFFFu : 0x80000000u;
  return (((ull)(u ^ msk)) << 32) | (unsigned)(127 - idx);
}

// Proj: LDS-tiled GEMM, register tile 2 rows x 12 cols per thread.
// grid 768 = 8 xcd * 96; XCD-swizzled so all blocks of an nw share one XCD's L2
// (dispatch round-robins blockIdx%8 across XCDs). Each block: 32 rows x 96 cols.
//   pj=0 -> Q = scale0*(vq@Wq^T)+b_q [r][c];  pj=1 -> K^T [c][r];  pj=2 -> VO.
// LDS: sWt[96][100] 38400B + sV[32][97] 12416B = 50816B -> 3 blocks/CU.
__global__ __launch_bounds__(128, 2) void proj_kernel(const float* __restrict__ v,
    const float* __restrict__ wq, const float* __restrict__ bq,
    const float* __restrict__ wk, const float* __restrict__ wo,
    const float* __restrict__ mb, const float* __restrict__ w_up,
    const float* __restrict__ b_up, float* __restrict__ ws) {
  int bid = blockIdx.x;
  int xcd = bid & 7;
  int m = bid >> 3;          // 0..95
  int g = m / 12;            // 0..7
  int rem = m - g * 12;      // 0..11
  int nw = (g << 3) | xcd;   // all 12 blocks of nw land on XCD (nw&7)
  int pj = rem >> 2, rh = rem & 3;
  const float* W = (pj == 0) ? wq : (pj == 1) ? wk : wo;
  __shared__ float sWt[96 * 100];   // [d][c] stride 100: 16B-aligned rows
  __shared__ float sV[32 * 97];     // [r][d] stride 97: conflict-free b32
  int t = threadIdx.x;
  int ty = t >> 3;   // 0..15 -> row pair
  int tx = t & 7;    // 0..7  -> col group of 12

  for (int k = 0; k < 72; ++k) {
    int idx = t + 128 * k;
    int c = idx / 96, d = idx - c * 96;
    sWt[d * 100 + c] = W[idx];
  }
  const float* Vg = v + (size_t)nw * PD + rh * (32 * D);
#pragma unroll
  for (int i = 0; i < 6; ++i) {
    int idx = (t + 128 * i) * 4;
    float4 x = *(const float4*)(Vg + idx);
    int r = idx / 96, d = idx - r * 96;
    float* p = &sV[r * 97 + d];
    p[0] = x.x; p[1] = x.y; p[2] = x.z; p[3] = x.w;
  }
  float scale0 = 0.f;
  if (pj == 0) {
    float a = b_up[0];
    for (int j = 0; j < LCH; ++j) a += w_up[j] * mb[j];
    scale0 = 1.f / (1.f + __expf(-a));
  }
  __syncthreads();

  float acc[2][12];
#pragma unroll
  for (int a = 0; a < 2; ++a)
#pragma unroll
    for (int j = 0; j < 12; ++j) acc[a][j] = 0.f;

  for (int d = 0; d < 96; ++d) {
    float va0 = sV[(ty * 2 + 0) * 97 + d];
    float va1 = sV[(ty * 2 + 1) * 97 + d];
    const float4* wp = (const float4*)&sWt[d * 100 + tx * 12];
    float4 w0 = wp[0], w1 = wp[1], w2 = wp[2];
    float wb[12] = {w0.x,w0.y,w0.z,w0.w, w1.x,w1.y,w1.z,w1.w, w2.x,w2.y,w2.z,w2.w};
#pragma unroll
    for (int j = 0; j < 12; ++j) {
      acc[0][j] += va0 * wb[j];
      acc[1][j] += va1 * wb[j];
    }
  }

  if (pj == 1) {
    float* ktp = ws + WS_KT + nw * PD;
#pragma unroll
    for (int a = 0; a < 2; ++a) {
      int r = rh * 32 + ty * 2 + a;
#pragma unroll
      for (int j = 0; j < 12; ++j)
        ktp[(tx * 12 + j) * P + r] = acc[a][j];
    }
  } else {
    float* outp = ws + ((pj == 0) ? WS_Q : WS_VO) + nw * PD + (rh * 32) * D;
    float4 bq4[3];
    if (pj == 0) {
      const float4* bp = (const float4*)(bq + tx * 12);
      bq4[0] = bp[0]; bq4[1] = bp[1]; bq4[2] = bp[2];
    }
#pragma unroll
    for (int a = 0; a < 2; ++a) {
      float* orow = outp + (ty * 2 + a) * D + tx * 12;
#pragma unroll
      for (int q = 0; q < 3; ++q) {
        float4 o;
        o.x = acc[a][4*q+0]; o.y = acc[a][4*q+1];
        o.z = acc[a][4*q+2]; o.w = acc[a][4*q+3];
        if (pj == 0) {
          o.x = scale0 * o.x + bq4[q].x; o.y = scale0 * o.y + bq4[q].y;
          o.z = scale0 * o.z + bq4[q].z; o.w = scale0 * o.w + bq4[q].w;
        }
        *(float4*)(orow + 4 * q) = o;
      }
    }
  }

  if (bid == 0 && t < GCH) {
    float a = b_up[t];
    for (int j = 0; j < LCH; ++j) a += w_up[t * LCH + j] * mb[j];
    ws[WS_SCALE + t] = 1.f / (1.f + __expf(-a));
  }
}

// Attn: 1-wave blocks (64 thr), 2 rows per wave, lane owns cols {2l, 2l+1}
// (float2 loads throughout). 4096 blocks, XCD-swizzled: all 64 blocks of an nw
// on XCD (nw&7) -> Kt/VO/Q stay in that XCD's L2 (1.15MB working set).
// Zero LDS; rank vs SALU-built u64 keys; PV T-broadcast via readlane.
__global__ __launch_bounds__(64, 4) void attn_kernel(const float* __restrict__ attn,
    const float* __restrict__ bo, const float* __restrict__ ws,
    float* __restrict__ out) {
  int bid = blockIdx.x;
  int lane = threadIdx.x;
  int xcd = bid & 7;
  int nw = ((bid >> 9) << 3) | xcd;   // nw&7 == xcd
  int rt = (bid >> 3) & 63;
  int p0 = rt * 2;
  const float* Kt  = ws + WS_KT + nw * PD;
  const float* VO  = ws + WS_VO + nw * PD;
  const float* Qb  = ws + WS_Q  + nw * PD + p0 * D;
  const float* Ab  = attn + (size_t)(nw * P + p0) * P;
  const float* scl = ws + WS_SCALE;

  // per-lane keys: cols 2l (even), 2l+1 (odd) of rows p0, p0+1
  ull ke[2], ko[2];
#pragma unroll
  for (int r = 0; r < 2; ++r) {
    float2 a2 = ((const float2*)(Ab + r * P))[lane];
    ke[r] = make_key(a2.x, 2 * lane);
    ko[r] = make_key(a2.y, 2 * lane + 1);
  }

  // exact stable top-100 rank; uniform side chunked to SGPRs
  int ce[2] = {0, 0}, co_[2] = {0, 0};
  for (int jb = 0; jb < P; jb += 8) {
    float aj[2][8];
#pragma unroll
    for (int r = 0; r < 2; ++r)
#pragma unroll
      for (int i = 0; i < 8; ++i) aj[r][i] = Ab[r * P + jb + i];
#pragma unroll
    for (int i = 0; i < 8; ++i) {
      int j = jb + i;
#pragma unroll
      for (int r = 0; r < 2; ++r) {
        ull kj = make_key(aj[r][i], j);   // uniform: SALU build
        ce[r]  += (kj > ke[r]) ? 1 : 0;   // v_cmp_gt_u64 + addc
        co_[r] += (kj > ko[r]) ? 1 : 0;
      }
    }
  }

  // S[r][2l], S[r][2l+1]: q uniform (chunked), Kt float2 coalesced
  float se[2] = {0, 0}, so[2] = {0, 0};
  for (int cb = 0; cb < D; cb += 8) {
    float q[2][8];
#pragma unroll
    for (int r = 0; r < 2; ++r)
#pragma unroll
      for (int i = 0; i < 8; ++i) q[r][i] = Qb[r * D + cb + i];
#pragma unroll
    for (int i = 0; i < 8; ++i) {
      float2 kv = ((const float2*)(Kt + (cb + i) * P))[lane];
#pragma unroll
      for (int r = 0; r < 2; ++r) {
        se[r] += q[r][i] * kv.x;
        so[r] += q[r][i] * kv.y;
      }
    }
  }

  // keep, position among kept (sorted idx order), scale, softmax, T
  float te[2], to[2];
  ull lm = (1ull << lane) - 1ull;
#pragma unroll
  for (int r = 0; r < 2; ++r) {
    bool kpe = ce[r] < SIM, kpo = co_[r] < SIM;
    ull be = __ballot(kpe), bo_ = __ballot(kpo);
    int pe = __popcll(be & lm) + __popcll(bo_ & lm);   // kept cols < 2l
    int po = pe + (kpe ? 1 : 0);                        // + col 2l itself
    float sve = kpe ? scl[1 + pe] : 0.f;
    float svo = kpo ? scl[1 + po] : 0.f;
    float xe = kpe ? sve * se[r] * RSQRT96 : -1e30f;
    float xo = kpo ? svo * so[r] * RSQRT96 : -1e30f;
    float mx = fmaxf(xe, xo);
#pragma unroll
    for (int off = 1; off < 64; off <<= 1) mx = fmaxf(mx, __shfl_xor(mx, off));
    float ee = kpe ? __expf(xe - mx) : 0.f;
    float eo = kpo ? __expf(xo - mx) : 0.f;
    float s = ee + eo;
#pragma unroll
    for (int off = 1; off < 64; off <<= 1) s += __shfl_xor(s, off);
    float inv = 1.f / s;
    te[r] = ee * inv * sve;
    to[r] = eo * inv * svo;
  }

  // out[r][c] = sum_j T[r][j]*VO[j][c] + b_o[c]; lane owns c={2lc,2lc+1}, lc<48
  int lc = (lane < 48) ? lane : 47;   // lanes 48-63 compute junk, don't store
  float2 o0 = {0.f, 0.f}, o1 = {0.f, 0.f};
#pragma unroll 8
  for (int j = 0; j < P; ++j) {
    float2 vo = ((const float2*)(VO + j * D))[lc];
    int h = j >> 1;
    float tv0 = __int_as_float(__builtin_amdgcn_readlane(
        __float_as_int((j & 1) ? to[0] : te[0]), h));
    float tv1 = __int_as_float(__builtin_amdgcn_readlane(
        __float_as_int((j & 1) ? to[1] : te[1]), h));
    o0.x += tv0 * vo.x; o0.y += tv0 * vo.y;
    o1.x += tv1 * vo.x; o1.y += tv1 * vo.y;
  }
  if (lane < 48) {
    float2 bb = ((const float2*)bo)[lane];
    float* op = out + (size_t)(nw * P + p0) * D;
    float2 r0; r0.x = o0.x + bb.x; r0.y = o0.y + bb.y;
    float2 r1; r1.x = o1.x + bb.x; r1.y = o1.y + bb.y;
    ((float2*)(op + 0 * D))[lane] = r0;
    ((float2*)(op + 1 * D))[lane] = r1;
  }
}

extern "C" void kernel_launch(void* const* d_in, const int* in_sizes, int n_in,
                              void* d_out, int out_size, void* d_ws, size_t ws_size,
                              hipStream_t stream) {
  const float* attn = (const float*)d_in[0];
  const float* v    = (const float*)d_in[1];
  const float* mb   = (const float*)d_in[2];
  // d_in[3]=w_sub, d_in[4]=b_sub: dead (softmax over singleton axis == 1)
  const float* w_up = (const float*)d_in[5];
  const float* b_up = (const float*)d_in[6];
  const float* w_q  = (const float*)d_in[7];
  const float* b_q  = (const float*)d_in[8];
  const float* w_k  = (const float*)d_in[9];
  // d_in[10]=b_k: constant shift per row -> drops out of softmax, unused
  const float* w_o  = (const float*)d_in[11];
  const float* b_o  = (const float*)d_in[12];
  float* out = (float*)d_out;
  float* ws = (float*)d_ws;

  hipLaunchKernelGGL(proj_kernel, dim3(768), dim3(128), 0, stream,
                     v, w_q, b_q, w_k, w_o, mb, w_up, b_up, ws);
  hipLaunchKernelGGL(attn_kernel, dim3(4096), dim3(64), 0, stream,
                     attn, b_o, ws, out);
}

// Round 7
// 64.764 us; speedup vs baseline: 1.4890x; 1.4890x over previous
//
#include <hip/hip_runtime.h>
#include <hip/hip_bf16.h>

// Geometry
#define NW 64          // N*W = 4*16
#define P 128          // rows per (n,w)
#define D 96           // channels
#define PD (P*D)
#define GCH 101
#define SIM 100
#define LCH 80
#define RSQRT96 0.10206207261596577f   // 1/sqrt(96)

// ws layout (float offsets)
#define WS_SCALE 0                     // 128 floats
#define WS_Q     128                   // 64*128*96   [r][c]
#define WS_KT    (128 + 786432)        // 64*96*128   [c][r] transposed
#define WS_VO    (128 + 2*786432)      // 64*128*96   [r][c]

typedef unsigned long long ull;

// key = (ordered_u32(value) << 32) | (127 - idx): strict total order,
// ties -> lower idx wins. Matches top_k + sort-index semantics exactly.
__device__ __forceinline__ ull make_key(float a, int idx) {
  unsigned u = __float_as_uint(a);
  unsigned msk = (u & 0x80000000u) ? 0xFFFFFFFFu : 0x80000000u;
  return (((ull)(u ^ msk)) << 32) | (unsigned)(127 - idx);
}

// Proj: LDS-tiled GEMM, register tile 2 rows x 12 cols per thread.
// grid 768 = 8 xcd * 96; XCD-swizzled so all blocks of an nw share one XCD's L2
// (dispatch round-robins blockIdx%8 across XCDs). Each block: 32 rows x 96 cols.
//   pj=0 -> Q = scale0*(vq@Wq^T)+b_q [r][c];  pj=1 -> K^T [c][r];  pj=2 -> VO.
// LDS: sWt[96][100] 38400B + sV[32][97] 12416B = 50816B -> 3 blocks/CU.
__global__ __launch_bounds__(128, 2) void proj_kernel(const float* __restrict__ v,
    const float* __restrict__ wq, const float* __restrict__ bq,
    const float* __restrict__ wk, const float* __restrict__ wo,
    const float* __restrict__ mb, const float* __restrict__ w_up,
    const float* __restrict__ b_up, float* __restrict__ ws) {
  int bid = blockIdx.x;
  int xcd = bid & 7;
  int m = bid >> 3;          // 0..95
  int g = m / 12;            // 0..7
  int rem = m - g * 12;      // 0..11
  int nw = (g << 3) | xcd;   // all 12 blocks of nw land on XCD (nw&7)
  int pj = rem >> 2, rh = rem & 3;
  const float* W = (pj == 0) ? wq : (pj == 1) ? wk : wo;
  __shared__ float sWt[96 * 100];   // [d][c] stride 100: 16B-aligned rows
  __shared__ float sV[32 * 97];     // [r][d] stride 97: conflict-free b32
  int t = threadIdx.x;
  int ty = t >> 3;   // 0..15 -> row pair
  int tx = t & 7;    // 0..7  -> col group of 12

  for (int k = 0; k < 72; ++k) {
    int idx = t + 128 * k;
    int c = idx / 96, d = idx - c * 96;
    sWt[d * 100 + c] = W[idx];
  }
  const float* Vg = v + (size_t)nw * PD + rh * (32 * D);
#pragma unroll
  for (int i = 0; i < 6; ++i) {
    int idx = (t + 128 * i) * 4;
    float4 x = *(const float4*)(Vg + idx);
    int r = idx / 96, d = idx - r * 96;
    float* p = &sV[r * 97 + d];
    p[0] = x.x; p[1] = x.y; p[2] = x.z; p[3] = x.w;
  }
  float scale0 = 0.f;
  if (pj == 0) {
    float a = b_up[0];
    for (int j = 0; j < LCH; ++j) a += w_up[j] * mb[j];
    scale0 = 1.f / (1.f + __expf(-a));
  }
  __syncthreads();

  float acc[2][12];
#pragma unroll
  for (int a = 0; a < 2; ++a)
#pragma unroll
    for (int j = 0; j < 12; ++j) acc[a][j] = 0.f;

  for (int d = 0; d < 96; ++d) {
    float va0 = sV[(ty * 2 + 0) * 97 + d];
    float va1 = sV[(ty * 2 + 1) * 97 + d];
    const float4* wp = (const float4*)&sWt[d * 100 + tx * 12];
    float4 w0 = wp[0], w1 = wp[1], w2 = wp[2];
    float wb[12] = {w0.x,w0.y,w0.z,w0.w, w1.x,w1.y,w1.z,w1.w, w2.x,w2.y,w2.z,w2.w};
#pragma unroll
    for (int j = 0; j < 12; ++j) {
      acc[0][j] += va0 * wb[j];
      acc[1][j] += va1 * wb[j];
    }
  }

  if (pj == 1) {
    float* ktp = ws + WS_KT + nw * PD;
#pragma unroll
    for (int a = 0; a < 2; ++a) {
      int r = rh * 32 + ty * 2 + a;
#pragma unroll
      for (int j = 0; j < 12; ++j)
        ktp[(tx * 12 + j) * P + r] = acc[a][j];
    }
  } else {
    float* outp = ws + ((pj == 0) ? WS_Q : WS_VO) + nw * PD + (rh * 32) * D;
    float4 bq4[3];
    if (pj == 0) {
      const float4* bp = (const float4*)(bq + tx * 12);
      bq4[0] = bp[0]; bq4[1] = bp[1]; bq4[2] = bp[2];
    }
#pragma unroll
    for (int a = 0; a < 2; ++a) {
      float* orow = outp + (ty * 2 + a) * D + tx * 12;
#pragma unroll
      for (int q = 0; q < 3; ++q) {
        float4 o;
        o.x = acc[a][4*q+0]; o.y = acc[a][4*q+1];
        o.z = acc[a][4*q+2]; o.w = acc[a][4*q+3];
        if (pj == 0) {
          o.x = scale0 * o.x + bq4[q].x; o.y = scale0 * o.y + bq4[q].y;
          o.z = scale0 * o.z + bq4[q].z; o.w = scale0 * o.w + bq4[q].w;
        }
        *(float4*)(orow + 4 * q) = o;
      }
    }
  }

  if (bid == 0 && t < GCH) {
    float a = b_up[t];
    for (int j = 0; j < LCH; ++j) a += w_up[t * LCH + j] * mb[j];
    ws[WS_SCALE + t] = 1.f / (1.f + __expf(-a));
  }
}

// Attn: 1-wave blocks (64 thr), 2 rows per wave, lane owns cols {2l, 2l+1}
// (float2 loads throughout). 4096 blocks, XCD-swizzled: all 64 blocks of an nw
// on XCD (nw&7) -> Kt/VO/Q stay in that XCD's L2 (1.15MB working set).
// Zero LDS; rank vs SALU-built u64 keys; PV T-broadcast via readlane.
// launch_bounds (64,2): VGPR cap 128 (cap = 256/min_waves!). (64,4) capped at
// 64 VGPR -> scratch spill -> 92MB HBM writes (R6 regression). Need ~110.
__global__ __launch_bounds__(64, 2) void attn_kernel(const float* __restrict__ attn,
    const float* __restrict__ bo, const float* __restrict__ ws,
    float* __restrict__ out) {
  int bid = blockIdx.x;
  int lane = threadIdx.x;
  int xcd = bid & 7;
  int nw = ((bid >> 9) << 3) | xcd;   // nw&7 == xcd
  int rt = (bid >> 3) & 63;
  int p0 = rt * 2;
  const float* Kt  = ws + WS_KT + nw * PD;
  const float* VO  = ws + WS_VO + nw * PD;
  const float* Qb  = ws + WS_Q  + nw * PD + p0 * D;
  const float* Ab  = attn + (size_t)(nw * P + p0) * P;
  const float* scl = ws + WS_SCALE;

  // per-lane keys: cols 2l (even), 2l+1 (odd) of rows p0, p0+1
  ull ke[2], ko[2];
#pragma unroll
  for (int r = 0; r < 2; ++r) {
    float2 a2 = ((const float2*)(Ab + r * P))[lane];
    ke[r] = make_key(a2.x, 2 * lane);
    ko[r] = make_key(a2.y, 2 * lane + 1);
  }

  // exact stable top-100 rank; uniform side chunked to SGPRs
  int ce[2] = {0, 0}, co_[2] = {0, 0};
  for (int jb = 0; jb < P; jb += 8) {
    float aj[2][8];
#pragma unroll
    for (int r = 0; r < 2; ++r)
#pragma unroll
      for (int i = 0; i < 8; ++i) aj[r][i] = Ab[r * P + jb + i];
#pragma unroll
    for (int i = 0; i < 8; ++i) {
      int j = jb + i;
#pragma unroll
      for (int r = 0; r < 2; ++r) {
        ull kj = make_key(aj[r][i], j);   // uniform: SALU build
        ce[r]  += (kj > ke[r]) ? 1 : 0;   // v_cmp_gt_u64 + addc
        co_[r] += (kj > ko[r]) ? 1 : 0;
      }
    }
  }

  // S[r][2l], S[r][2l+1]: q uniform (chunked), Kt float2 coalesced
  float se[2] = {0, 0}, so[2] = {0, 0};
  for (int cb = 0; cb < D; cb += 8) {
    float q[2][8];
#pragma unroll
    for (int r = 0; r < 2; ++r)
#pragma unroll
      for (int i = 0; i < 8; ++i) q[r][i] = Qb[r * D + cb + i];
#pragma unroll
    for (int i = 0; i < 8; ++i) {
      float2 kv = ((const float2*)(Kt + (cb + i) * P))[lane];
#pragma unroll
      for (int r = 0; r < 2; ++r) {
        se[r] += q[r][i] * kv.x;
        so[r] += q[r][i] * kv.y;
      }
    }
  }

  // keep, position among kept (sorted idx order), scale, softmax, T
  float te[2], to[2];
  ull lm = (1ull << lane) - 1ull;
#pragma unroll
  for (int r = 0; r < 2; ++r) {
    bool kpe = ce[r] < SIM, kpo = co_[r] < SIM;
    ull be = __ballot(kpe), bo_ = __ballot(kpo);
    int pe = __popcll(be & lm) + __popcll(bo_ & lm);   // kept cols < 2l
    int po = pe + (kpe ? 1 : 0);                        // + col 2l itself
    float sve = kpe ? scl[1 + pe] : 0.f;
    float svo = kpo ? scl[1 + po] : 0.f;
    float xe = kpe ? sve * se[r] * RSQRT96 : -1e30f;
    float xo = kpo ? svo * so[r] * RSQRT96 : -1e30f;
    float mx = fmaxf(xe, xo);
#pragma unroll
    for (int off = 1; off < 64; off <<= 1) mx = fmaxf(mx, __shfl_xor(mx, off));
    float ee = kpe ? __expf(xe - mx) : 0.f;
    float eo = kpo ? __expf(xo - mx) : 0.f;
    float s = ee + eo;
#pragma unroll
    for (int off = 1; off < 64; off <<= 1) s += __shfl_xor(s, off);
    float inv = 1.f / s;
    te[r] = ee * inv * sve;
    to[r] = eo * inv * svo;
  }

  // out[r][c] = sum_j T[r][j]*VO[j][c] + b_o[c]; lane owns c={2lc,2lc+1}, lc<48
  int lc = (lane < 48) ? lane : 47;   // lanes 48-63 compute junk, don't store
  float2 o0 = {0.f, 0.f}, o1 = {0.f, 0.f};
#pragma unroll 8
  for (int j = 0; j < P; ++j) {
    float2 vo = ((const float2*)(VO + j * D))[lc];
    int h = j >> 1;
    float tv0 = __int_as_float(__builtin_amdgcn_readlane(
        __float_as_int((j & 1) ? to[0] : te[0]), h));
    float tv1 = __int_as_float(__builtin_amdgcn_readlane(
        __float_as_int((j & 1) ? to[1] : te[1]), h));
    o0.x += tv0 * vo.x; o0.y += tv0 * vo.y;
    o1.x += tv1 * vo.x; o1.y += tv1 * vo.y;
  }
  if (lane < 48) {
    float2 bb = ((const float2*)bo)[lane];
    float* op = out + (size_t)(nw * P + p0) * D;
    float2 r0; r0.x = o0.x + bb.x; r0.y = o0.y + bb.y;
    float2 r1; r1.x = o1.x + bb.x; r1.y = o1.y + bb.y;
    ((float2*)(op + 0 * D))[lane] = r0;
    ((float2*)(op + 1 * D))[lane] = r1;
  }
}

extern "C" void kernel_launch(void* const* d_in, const int* in_sizes, int n_in,
                              void* d_out, int out_size, void* d_ws, size_t ws_size,
                              hipStream_t stream) {
  const float* attn = (const float*)d_in[0];
  const float* v    = (const float*)d_in[1];
  const float* mb   = (const float*)d_in[2];
  // d_in[3]=w_sub, d_in[4]=b_sub: dead (softmax over singleton axis == 1)
  const float* w_up = (const float*)d_in[5];
  const float* b_up = (const float*)d_in[6];
  const float* w_q  = (const float*)d_in[7];
  const float* b_q  = (const float*)d_in[8];
  const float* w_k  = (const float*)d_in[9];
  // d_in[10]=b_k: constant shift per row -> drops out of softmax, unused
  const float* w_o  = (const float*)d_in[11];
  const float* b_o  = (const float*)d_in[12];
  float* out = (float*)d_out;
  float* ws = (float*)d_ws;

  hipLaunchKernelGGL(proj_kernel, dim3(768), dim3(128), 0, stream,
                     v, w_q, b_q, w_k, w_o, mb, w_up, b_up, ws);
  hipLaunchKernelGGL(attn_kernel, dim3(4096), dim3(64), 0, stream,
                     attn, b_o, ws, out);
}